// Round 5
// baseline (1218.272 us; speedup 1.0000x reference)
//
#include <hip/hip_runtime.h>
#include <hip/hip_bf16.h>

#define NN 50000   // nodes
#define NE 400000  // edges
#define DD 384     // input dim
#define HC 512     // heads * per-head dim (4 heads x 128)

typedef unsigned int u32;
typedef unsigned short u16;
typedef __attribute__((ext_vector_type(8))) short bf16x8;  // 8 bf16 (4 VGPRs)
typedef __attribute__((ext_vector_type(4))) float f32x4;

#define AS1 __attribute__((address_space(1)))
#define AS3 __attribute__((address_space(3)))

__device__ __forceinline__ float bflo(u32 u){ return __uint_as_float(u << 16); }
__device__ __forceinline__ float bfhi(u32 u){ return __uint_as_float(u & 0xFFFF0000u); }
__device__ __forceinline__ u16 f2bf(float f){
    u32 u = __float_as_uint(f);
    return (u16)((u + 0x7FFFu + ((u >> 16) & 1u)) >> 16);   // RNE
}
__device__ __forceinline__ u32 pack2(float a, float b){
    return (u32)f2bf(a) | ((u32)f2bf(b) << 16);
}

// ---------------------------------------------------------------------------
// A-resident QKVS GEMM: out[n, 2048] = A[n, K] * W[2048, K]^T + bias,
// scattered to Q/K/V/S (bf16, stride 512).
// Block: 128 rows x (NO=8 col-tiles of 128), grid (ceil(n/128), 2).
// A (bf16-converted) resident in LDS for ALL K: [128][K], XOR-swizzled
// per 16B chunk (chunk ^= row&7). B double-buffered [2][128][128B],
// staged via global_load_lds with pre-swizzled source; stage(s+1) issued
// before compute(s) so HBM/L2 latency hides under MFMA (one barrier/K-step).
// 4 waves (2x2), wave owns 64x64 of each 128x128 tile.
// ---------------------------------------------------------------------------
template<bool AFP32, int K>
__global__ __launch_bounds__(256)
void gemm_fullA(const void* __restrict__ Ap, const u16* __restrict__ Wb,
                const float* __restrict__ bias,
                u16* __restrict__ oQ, u16* __restrict__ oK,
                u16* __restrict__ oV, u16* __restrict__ oS, int n)
{
    constexpr int NK  = K / 64;         // K-steps
    constexpr int CPR = K / 8;          // 16B chunks per A row
    constexpr int NO  = 8;              // col-tiles per block
    constexpr int NS  = NO * NK;
    __shared__ char smA[128 * K * 2];
    __shared__ char smB[2][16384];

    const int tid  = threadIdx.x;
    const int lane = tid & 63;
    const int w    = tid >> 6;
    const int wr   = w >> 1, wc = w & 1;
    const int m0   = blockIdx.x * 128;
    const int obase = blockIdx.y * NO;  // first col-tile index
    const int r16  = lane & 15;
    const int kq   = lane >> 4;
    const int swz  = (r16 & 7) << 4;

    // ---- stage A for all K (once) ----
    if constexpr (AFP32) {              // fp32 -> bf16 via registers
        const float* Af = (const float*)Ap;
        #pragma unroll
        for (int p = 0; p < (128 * CPR) / 256; ++p) {
            int ci  = p * 256 + tid;
            int row = ci / CPR, pc = ci % CPR;
            int lc  = (pc & ~7) | ((pc ^ row) & 7);
            int gr  = m0 + row; if (gr >= n) gr = n - 1;
            const float* g = Af + (size_t)gr * K + lc * 8;
            float4 f0 = *(const float4*)g;
            float4 f1 = *(const float4*)(g + 4);
            uint4 o;
            o.x = pack2(f0.x, f0.y); o.y = pack2(f0.z, f0.w);
            o.z = pack2(f1.x, f1.y); o.w = pack2(f1.z, f1.w);
            *(uint4*)(smA + (size_t)ci * 16) = o;
        }
    } else {                            // bf16: direct global->LDS DMA
        const u16* Ab = (const u16*)Ap;
        #pragma unroll
        for (int p = 0; p < (128 * CPR) / 256; ++p) {
            int ci  = p * 256 + tid;
            int row = ci / CPR, pc = ci % CPR;
            int lc  = (pc & ~7) | ((pc ^ row) & 7);
            int gr  = m0 + row; if (gr >= n) gr = n - 1;
            __builtin_amdgcn_global_load_lds((const AS1 u32*)(Ab + (size_t)gr * K + lc * 8),
                                             (AS3 u32*)(smA + (size_t)ci * 16), 16, 0, 0);
        }
    }

    // ---- stage B(s=0) ----
    {
        int o0 = obase * 128;
        #pragma unroll
        for (int p = 0; p < 4; ++p) {
            int ci = p * 256 + tid;
            int row = ci >> 3, pc = ci & 7;
            int lc = pc ^ (row & 7);
            const u16* g = Wb + (size_t)(o0 + row) * K + lc * 8;
            __builtin_amdgcn_global_load_lds((const AS1 u32*)g,
                                             (AS3 u32*)(smB[0] + ci * 16), 16, 0, 0);
        }
    }
    __syncthreads();                    // drains A + B0 (vmcnt before barrier)

    f32x4 acc[4][4] = {};

    for (int j = 0; j < NO; ++j) {
        for (int kt = 0; kt < NK; ++kt) {
            const int s = j * NK + kt;
            if (s + 1 < NS) {           // prefetch next B tile into other buffer
                int ns = s + 1;
                int nj = ns / NK, nkt = ns - nj * NK;
                int o0n = (obase + nj) * 128;
                #pragma unroll
                for (int p = 0; p < 4; ++p) {
                    int ci = p * 256 + tid;
                    int row = ci >> 3, pc = ci & 7;
                    int lc = pc ^ (row & 7);
                    const u16* g = Wb + (size_t)(o0n + row) * K + nkt * 64 + lc * 8;
                    __builtin_amdgcn_global_load_lds((const AS1 u32*)g,
                                                     (AS3 u32*)(smB[ns & 1] + ci * 16), 16, 0, 0);
                }
            }
            const char* pb = smB[s & 1] + (wc * 64) * 128;
            #pragma unroll
            for (int kk = 0; kk < 2; ++kk) {
                const int kbB = kk * 64 + kq * 16;
                const int chA = kt * 8 + kk * 4 + kq;
                bf16x8 av[4], bv[4];
                #pragma unroll
                for (int i = 0; i < 4; ++i) {
                    int rowA = wr * 64 + i * 16 + r16;
                    av[i] = *(const bf16x8*)(smA + (size_t)rowA * (K * 2)
                                             + ((chA ^ (rowA & 7)) << 4));
                    bv[i] = *(const bf16x8*)(pb + (i * 16 + r16) * 128 + (kbB ^ swz));
                }
                #pragma unroll
                for (int mi = 0; mi < 4; ++mi)
                    #pragma unroll
                    for (int ni = 0; ni < 4; ++ni)
                        acc[mi][ni] = __builtin_amdgcn_mfma_f32_16x16x32_bf16(
                            av[mi], bv[ni], acc[mi][ni], 0, 0, 0);
            }
            __syncthreads();            // B(s+1) landed; smB[s&1] free for s+2
        }
        // ---- epilogue for col-tile j; C/D: col=lane&15, row=(lane>>4)*4+reg ----
        {
            int o0 = (obase + j) * 128;
            int q  = o0 >> 9;
            u16* outp = (q == 0) ? oQ : (q == 1) ? oK : (q == 2) ? oV : oS;
            int cb = (o0 & 511) + wc * 64;
            #pragma unroll
            for (int ni = 0; ni < 4; ++ni) {
                int col = cb + ni * 16 + r16;
                float b = bias[o0 + wc * 64 + ni * 16 + r16];
                #pragma unroll
                for (int mi = 0; mi < 4; ++mi) {
                    #pragma unroll
                    for (int r = 0; r < 4; ++r) {
                        int gr = m0 + wr * 64 + mi * 16 + kq * 4 + r;
                        if (gr < n) outp[(size_t)gr * 512 + col] = f2bf(acc[mi][ni][r] + b);
                        acc[mi][ni][r] = 0.f;
                    }
                }
            }
        }
    }
}

// ---------------------------------------------------------------------------
// Plain 128x128-tile MFMA GEMM (fp32 out) — used for the output projection.
// ---------------------------------------------------------------------------
__global__ __launch_bounds__(256)
void gemm_mfma_f(const u16* __restrict__ Ab, const u16* __restrict__ Wb,
                 const float* __restrict__ bias, float* __restrict__ oF,
                 int n, int K, int Ototal)
{
    __shared__ char smA[128 * 128];
    __shared__ char smB[128 * 128];

    const int tid  = threadIdx.x;
    const int lane = tid & 63;
    const int w    = tid >> 6;
    const int wr   = w >> 1, wc = w & 1;
    const int m0   = blockIdx.x * 128;
    const int o0   = blockIdx.y * 128;
    const int r16  = lane & 15;
    const int kq   = lane >> 4;
    const int swz  = (r16 & 7) << 4;

    f32x4 acc[4][4] = {};

    const int nkt = K >> 6;
    for (int kt = 0; kt < nkt; ++kt) {
        const int k0 = kt << 6;
        __syncthreads();
        #pragma unroll
        for (int p = 0; p < 4; ++p) {
            int ci = p * 256 + tid;
            int row = ci >> 3, pc = ci & 7;
            int lc = pc ^ (row & 7);
            const u16* g = Wb + (size_t)(o0 + row) * K + k0 + lc * 8;
            __builtin_amdgcn_global_load_lds((const AS1 u32*)g,
                                             (AS3 u32*)(smB + ci * 16), 16, 0, 0);
        }
        #pragma unroll
        for (int p = 0; p < 4; ++p) {
            int ci = p * 256 + tid;
            int row = ci >> 3, pc = ci & 7;
            int lc = pc ^ (row & 7);
            int gr = m0 + row; if (gr >= n) gr = n - 1;
            const u16* g = Ab + (size_t)gr * K + k0 + lc * 8;
            __builtin_amdgcn_global_load_lds((const AS1 u32*)g,
                                             (AS3 u32*)(smA + ci * 16), 16, 0, 0);
        }
        __syncthreads();
        const char* pa = smA + (wr * 64) * 128;
        const char* pb = smB + (wc * 64) * 128;
        #pragma unroll
        for (int kk = 0; kk < 2; ++kk) {
            const int kb = kk * 64 + kq * 16;
            bf16x8 av[4], bv[4];
            #pragma unroll
            for (int i = 0; i < 4; ++i) {
                av[i] = *(const bf16x8*)(pa + (i * 16 + r16) * 128 + (kb ^ swz));
                bv[i] = *(const bf16x8*)(pb + (i * 16 + r16) * 128 + (kb ^ swz));
            }
            #pragma unroll
            for (int mi = 0; mi < 4; ++mi)
                #pragma unroll
                for (int ni = 0; ni < 4; ++ni)
                    acc[mi][ni] = __builtin_amdgcn_mfma_f32_16x16x32_bf16(
                        av[mi], bv[ni], acc[mi][ni], 0, 0, 0);
        }
    }

    const int cb = o0 + wc * 64;
    #pragma unroll
    for (int ni = 0; ni < 4; ++ni) {
        int col = cb + ni * 16 + r16;
        float b = bias[col];
        #pragma unroll
        for (int mi = 0; mi < 4; ++mi)
            #pragma unroll
            for (int r = 0; r < 4; ++r) {
                int gr = m0 + wr * 64 + mi * 16 + kq * 4 + r;
                if (gr < n) oF[(size_t)gr * Ototal + col] = acc[mi][ni][r] + b;
            }
    }
}

// ---------------------------------------------------------------------------
// weight fp32 -> bf16 convert (count % 8 == 0)
__global__ __launch_bounds__(256)
void cvt_w(const float* __restrict__ src, u16* __restrict__ dst, int n8)
{
    int i = blockIdx.x * 256 + threadIdx.x;
    if (i >= n8) return;
    const float4* s = (const float4*)src + (size_t)i * 2;
    float4 f0 = s[0], f1 = s[1];
    uint4 o;
    o.x = pack2(f0.x, f0.y); o.y = pack2(f0.z, f0.w);
    o.z = pack2(f1.x, f1.y); o.w = pack2(f1.z, f1.w);
    ((uint4*)dst)[i] = o;
}

// bias arena: [0..2047]=layer0 qkvs, [2048..4095]=layer1 qkvs, [4096..4479]=out
__global__ __launch_bounds__(256)
void pack_bias(const float* q0, const float* k0, const float* v0, const float* s0,
               const float* q1, const float* k1, const float* v1, const float* s1,
               const float* ob, float* __restrict__ dst)
{
    int i = blockIdx.x * 256 + threadIdx.x;
    if (i >= 4480) return;
    float v;
    if (i < 2048) {
        int j = i & 511, q = i >> 9;
        v = (q == 0 ? q0 : q == 1 ? k0 : q == 2 ? v0 : s0)[j];
    } else if (i < 4096) {
        int j = i - 2048; int q = j >> 9; j &= 511;
        v = (q == 0 ? q1 : q == 1 ? k1 : q == 2 ? v1 : s1)[j];
    } else {
        v = ob[i - 4096];
    }
    dst[i] = v;
}

// ---------------------------------------------------------------------------
// CSR build (order within bucket nondeterministic -> only permutes fp adds)
// ---------------------------------------------------------------------------
__global__ __launch_bounds__(256)
void zero_deg(int* __restrict__ deg)
{
    int i = blockIdx.x * 256 + threadIdx.x;
    if (i < NN) deg[i] = 0;
}

__global__ __launch_bounds__(256)
void hist_dst(const int* __restrict__ dst, int* __restrict__ deg)
{
    int e = blockIdx.x * 256 + threadIdx.x;
    if (e < NE) atomicAdd(&deg[dst[e]], 1);
}

__global__ __launch_bounds__(1024)
void scan_deg(const int* __restrict__ deg, int* __restrict__ rowptr,
              int* __restrict__ cursor)
{
    __shared__ int buf[1024];
    __shared__ int carry;
    int tid = threadIdx.x;
    if (tid == 0) carry = 0;
    __syncthreads();
    for (int base = 0; base < NN; base += 1024) {
        int i = base + tid;
        int v = (i < NN) ? deg[i] : 0;
        buf[tid] = v;
        __syncthreads();
        #pragma unroll
        for (int off = 1; off < 1024; off <<= 1) {
            int t = (tid >= off) ? buf[tid - off] : 0;
            __syncthreads();
            buf[tid] += t;
            __syncthreads();
        }
        int excl = carry + buf[tid] - v;
        if (i < NN) { rowptr[i] = excl; cursor[i] = excl; }
        __syncthreads();
        if (tid == 0) carry += buf[1023];
        __syncthreads();
    }
    if (tid == 0) rowptr[NN] = NE;
}

__global__ __launch_bounds__(256)
void scatter_edges(const int* __restrict__ src, const int* __restrict__ dst,
                   int* __restrict__ cursor, int* __restrict__ esrc_ord)
{
    int e = blockIdx.x * 256 + threadIdx.x;
    if (e >= NE) return;
    int pos = atomicAdd(&cursor[dst[e]], 1);
    esrc_ord[pos] = src[e];
}

// ---------------------------------------------------------------------------
// Fused per-node attention: one 64-lane wave per dst node; online softmax.
// Lane owns 8 contiguous channels; 16-lane group = one head.
// out = bf16(relu(agg + skip)), skip is bf16.
// ---------------------------------------------------------------------------
__global__ __launch_bounds__(256)
void node_attn(const u16* __restrict__ Qb, const u16* __restrict__ Kb,
               const u16* __restrict__ Vb, const int* __restrict__ rowptr,
               const int* __restrict__ esrc, const u16* __restrict__ skipb,
               u16* __restrict__ outb)
{
    int d = blockIdx.x * 4 + (threadIdx.x >> 6);
    if (d >= NN) return;
    int lane = threadIdx.x & 63;

    uint4 qv = *((const uint4*)(Qb + (size_t)d * HC) + lane);
    float q[8] = { bflo(qv.x), bfhi(qv.x), bflo(qv.y), bfhi(qv.y),
                   bflo(qv.z), bfhi(qv.z), bflo(qv.w), bfhi(qv.w) };

    int beg = rowptr[d], end = rowptr[d + 1];
    float m = -INFINITY, den = 0.f;
    float acc[8] = {};

    for (int i = beg; i < end; ++i) {
        int s = esrc[i];
        uint4 kv = *((const uint4*)(Kb + (size_t)s * HC) + lane);
        float sum = q[0] * bflo(kv.x) + q[1] * bfhi(kv.x)
                  + q[2] * bflo(kv.y) + q[3] * bfhi(kv.y)
                  + q[4] * bflo(kv.z) + q[5] * bfhi(kv.z)
                  + q[6] * bflo(kv.w) + q[7] * bfhi(kv.w);
        #pragma unroll
        for (int off = 1; off < 16; off <<= 1) sum += __shfl_xor(sum, off, 64);
        float alpha = sum * 0.08838834764831845f;

        float mnew  = fmaxf(m, alpha);
        float scale = __expf(m - mnew);      // first edge: exp(-inf)=0
        float p     = __expf(alpha - mnew);
        den = den * scale + p;

        uint4 vv = *((const uint4*)(Vb + (size_t)s * HC) + lane);
        acc[0] = acc[0] * scale + p * bflo(vv.x);
        acc[1] = acc[1] * scale + p * bfhi(vv.x);
        acc[2] = acc[2] * scale + p * bflo(vv.y);
        acc[3] = acc[3] * scale + p * bfhi(vv.y);
        acc[4] = acc[4] * scale + p * bflo(vv.z);
        acc[5] = acc[5] * scale + p * bfhi(vv.z);
        acc[6] = acc[6] * scale + p * bflo(vv.w);
        acc[7] = acc[7] * scale + p * bfhi(vv.w);
        m = mnew;
    }

    float inv = 1.f / (den + 1e-16f);
    size_t base = (size_t)d * HC + lane * 8;
    uint4 sv = *((const uint4*)(skipb + base));
    float sk[8] = { bflo(sv.x), bfhi(sv.x), bflo(sv.y), bfhi(sv.y),
                    bflo(sv.z), bfhi(sv.z), bflo(sv.w), bfhi(sv.w) };
    uint4 o;
    o.x = pack2(fmaxf(acc[0] * inv + sk[0], 0.f), fmaxf(acc[1] * inv + sk[1], 0.f));
    o.y = pack2(fmaxf(acc[2] * inv + sk[2], 0.f), fmaxf(acc[3] * inv + sk[3], 0.f));
    o.z = pack2(fmaxf(acc[4] * inv + sk[4], 0.f), fmaxf(acc[5] * inv + sk[5], 0.f));
    o.w = pack2(fmaxf(acc[6] * inv + sk[6], 0.f), fmaxf(acc[7] * inv + sk[7], 0.f));
    *(uint4*)(outb + base) = o;
}

// ---------------------------------------------------------------------------
extern "C" void kernel_launch(void* const* d_in, const int* in_sizes, int n_in,
                              void* d_out, int out_size, void* d_ws, size_t ws_size,
                              hipStream_t stream)
{
    const float* x   = (const float*)d_in[0];
    const int* ei    = (const int*)d_in[1];
    const int* esrc  = ei;
    const int* edst  = ei + NE;
    const float* q0w = (const float*)d_in[2];  const float* q0b = (const float*)d_in[3];
    const float* k0w = (const float*)d_in[4];  const float* k0b = (const float*)d_in[5];
    const float* v0w = (const float*)d_in[6];  const float* v0b = (const float*)d_in[7];
    const float* s0w = (const float*)d_in[8];  const float* s0b = (const float*)d_in[9];
    const float* q1w = (const float*)d_in[10]; const float* q1b = (const float*)d_in[11];
    const float* k1w = (const float*)d_in[12]; const float* k1b = (const float*)d_in[13];
    const float* v1w = (const float*)d_in[14]; const float* v1b = (const float*)d_in[15];
    const float* s1w = (const float*)d_in[16]; const float* s1b = (const float*)d_in[17];
    const float* ow  = (const float*)d_in[18]; const float* obs = (const float*)d_in[19];

    // ---- workspace (~209 MB) ----
    char* p = (char*)d_ws;
    auto take = [&](size_t bytes) { void* r = (void*)p; p += (bytes + 255) & ~(size_t)255; return r; };
    u16*   Qb     = (u16*)take((size_t)NN * HC * 2);       // 51.2 MB
    u16*   Vb     = (u16*)take((size_t)NN * HC * 2);       // 51.2 MB
    u16*   Hb     = (u16*)take((size_t)NN * HC * 2);       // 51.2 MB
    u16*   Sb     = (u16*)take((size_t)NN * HC * 2);       // 51.2 MB (bf16 skip)
    u16*   Wc0    = (u16*)take((size_t)2048 * DD * 2);     // 1.57 MB
    u16*   Wc1    = (u16*)take((size_t)2048 * HC * 2);     // 2.10 MB
    u16*   WcO    = (u16*)take((size_t)DD * HC * 2);       // 0.39 MB
    float* barena = (float*)take(4480 * 4);                // 17.9 KB

    // ---- scratch carved from d_out (dead before final GEMM overwrites all) ----
    char* dob = (char*)d_out;
    u16* Kb       = (u16*)dob;                             // 51.2 MB
    int* deg      = (int*)(dob + 51200000);
    int* rowptr   = (int*)(dob + 51400192);                // NN+1
    int* cursor   = (int*)(dob + 51600384);
    int* esrc_ord = (int*)(dob + 51800576);                // 1.6 MB

    dim3 blk(256);
    int gN   = (NN + 255) / 256;
    int gE   = (NE + 255) / 256;
    int gnod = (NN + 3) / 4;
    dim3 gq((NN + 127) / 128, 2);       // A-resident QKVS GEMM, CSPLIT=2
    dim3 go((NN + 127) / 128, 3);       // out-proj: O=384

    // ---- weight/bias prep ----
    pack_bias<<<(4480 + 255) / 256, blk, 0, stream>>>(q0b, k0b, v0b, s0b,
                                                      q1b, k1b, v1b, s1b, obs, barena);
    const int w0n8 = 512 * DD / 8, w1n8 = 512 * HC / 8, won8 = DD * HC / 8;
    cvt_w<<<(w0n8 + 255) / 256, blk, 0, stream>>>(q0w, Wc0 + 0 * 512 * DD, w0n8);
    cvt_w<<<(w0n8 + 255) / 256, blk, 0, stream>>>(k0w, Wc0 + 1 * 512 * DD, w0n8);
    cvt_w<<<(w0n8 + 255) / 256, blk, 0, stream>>>(v0w, Wc0 + 2 * 512 * DD, w0n8);
    cvt_w<<<(w0n8 + 255) / 256, blk, 0, stream>>>(s0w, Wc0 + 3 * 512 * DD, w0n8);
    cvt_w<<<(w1n8 + 255) / 256, blk, 0, stream>>>(q1w, Wc1 + 0 * 512 * HC, w1n8);
    cvt_w<<<(w1n8 + 255) / 256, blk, 0, stream>>>(k1w, Wc1 + 1 * 512 * HC, w1n8);
    cvt_w<<<(w1n8 + 255) / 256, blk, 0, stream>>>(v1w, Wc1 + 2 * 512 * HC, w1n8);
    cvt_w<<<(w1n8 + 255) / 256, blk, 0, stream>>>(s1w, Wc1 + 3 * 512 * HC, w1n8);
    cvt_w<<<(won8 + 255) / 256, blk, 0, stream>>>(ow, WcO, won8);

    // ---- CSR build ----
    zero_deg      <<<gN, blk, 0, stream>>>(deg);
    hist_dst      <<<gE, blk, 0, stream>>>(edst, deg);
    scan_deg      <<<1, 1024, 0, stream>>>(deg, rowptr, cursor);
    scatter_edges <<<gE, blk, 0, stream>>>(esrc, edst, cursor, esrc_ord);

    // ---- layer 0 (A = x fp32, K=384) ----
    gemm_fullA<true, DD><<<gq, blk, 0, stream>>>(x, Wc0, barena, Qb, Kb, Vb, Sb, NN);
    node_attn<<<gnod, blk, 0, stream>>>(Qb, Kb, Vb, rowptr, esrc_ord, Sb, Hb);

    // ---- layer 1 (A = Hb bf16, K=512) ----
    gemm_fullA<false, HC><<<gq, blk, 0, stream>>>(Hb, Wc1, barena + 2048, Qb, Kb, Vb, Sb, NN);
    node_attn<<<gnod, blk, 0, stream>>>(Qb, Kb, Vb, rowptr, esrc_ord, Sb, Hb);

    // ---- output projection (fp32 out, overwrites ALL of d_out) ----
    gemm_mfma_f<<<go, blk, 0, stream>>>(Hb, WcO, barena + 4096, (float*)d_out, NN, HC, DD);
}

// Round 6
// 964.092 us; speedup vs baseline: 1.2636x; 1.2636x over previous
//
#include <hip/hip_runtime.h>
#include <hip/hip_bf16.h>

#define NN 50000   // nodes
#define NE 400000  // edges
#define DD 384     // input dim
#define HC 512     // heads * per-head dim (4 heads x 128)

typedef unsigned int u32;
typedef unsigned short u16;
typedef __attribute__((ext_vector_type(8))) short bf16x8;  // 8 bf16 (4 VGPRs)
typedef __attribute__((ext_vector_type(4))) float f32x4;

#define AS1 __attribute__((address_space(1)))
#define AS3 __attribute__((address_space(3)))

__device__ __forceinline__ float bflo(u32 u){ return __uint_as_float(u << 16); }
__device__ __forceinline__ float bfhi(u32 u){ return __uint_as_float(u & 0xFFFF0000u); }
__device__ __forceinline__ u16 f2bf(float f){
    u32 u = __float_as_uint(f);
    return (u16)((u + 0x7FFFu + ((u >> 16) & 1u)) >> 16);   // RNE
}
__device__ __forceinline__ u32 pack2(float a, float b){
    return (u32)f2bf(a) | ((u32)f2bf(b) << 16);
}

// ---------------------------------------------------------------------------
// MFMA GEMM: Y[n, O] = A[n, K] * W[O, K]^T + bias  (round-4 structure:
// 128x128 tile, BK=64, 4 waves 2x2, 32KB LDS, XOR-swizzled chunks).
// NEW: 1D grid + bijective XCD swizzle (m204), col-tile fastest within an
// XCD so each XCD's concurrent window covers whole row-panels -> A panel
// fetched ~once per XCD instead of once per col-tile sweep.
// QKVS: NT=16 col-tiles, scatter to Q/K/V/S (bf16, stride 512).
// else: fp32 out oF (stride Ototal), NT=Ototal/128.
// ---------------------------------------------------------------------------
template<bool AFP32, bool QKVS>
__global__ __launch_bounds__(256)
void gemm_mfma(const void* __restrict__ Ap, const u16* __restrict__ Wb,
               const float* __restrict__ bias,
               u16* __restrict__ oQ, u16* __restrict__ oK,
               u16* __restrict__ oV, u16* __restrict__ oS,
               float* __restrict__ oF,
               int n, int K, int Ototal, int NT)
{
    __shared__ char smA[128 * 128];
    __shared__ char smB[128 * 128];

    // ---- bijective XCD swizzle: XCD x owns contiguous tile range ----
    const int nb  = gridDim.x;
    const int d   = blockIdx.x;
    const int q8  = nb >> 3, r8 = nb & 7;
    const int xcd = d & 7, g = d >> 3;
    const int t   = (xcd < r8 ? xcd * (q8 + 1) : r8 * (q8 + 1) + (xcd - r8) * q8) + g;
    const int m0  = (t / NT) * 128;     // row panel
    const int o0  = (t % NT) * 128;     // col tile (fastest within XCD)

    const int tid  = threadIdx.x;
    const int lane = tid & 63;
    const int w    = tid >> 6;
    const int wr   = w >> 1, wc = w & 1;
    const int r16  = lane & 15;
    const int kq   = lane >> 4;            // 0..3
    const int swz  = (r16 & 7) << 4;       // read-side XOR

    f32x4 acc[4][4] = {};

    const int nkt = K >> 6;
    for (int kt = 0; kt < nkt; ++kt) {
        const int k0 = kt << 6;
        __syncthreads();                   // protect LDS from previous reads
        // ---- stage B (bf16) via global_load_lds, source pre-swizzled ----
        #pragma unroll
        for (int p = 0; p < 4; ++p) {
            int ci = p * 256 + tid;        // 16B chunk index, 8 chunks/row
            int row = ci >> 3, pc = ci & 7;
            int lc = pc ^ (row & 7);
            const u16* gptr = Wb + (size_t)(o0 + row) * K + k0 + lc * 8;
            __builtin_amdgcn_global_load_lds((const AS1 u32*)gptr,
                                             (AS3 u32*)(smB + ci * 16), 16, 0, 0);
        }
        // ---- stage A ----
        if constexpr (AFP32) {             // fp32 -> bf16 convert via registers
            const float* Af = (const float*)Ap;
            #pragma unroll
            for (int p = 0; p < 4; ++p) {
                int ci = p * 256 + tid;
                int row = ci >> 3, lc = ci & 7;
                int gr = m0 + row; if (gr >= n) gr = n - 1;
                const float* gp = Af + (size_t)gr * K + k0 + lc * 8;
                float4 f0 = *(const float4*)gp;
                float4 f1 = *(const float4*)(gp + 4);
                uint4 o;
                o.x = pack2(f0.x, f0.y); o.y = pack2(f0.z, f0.w);
                o.z = pack2(f1.x, f1.y); o.w = pack2(f1.z, f1.w);
                int pc = lc ^ (row & 7);
                *(uint4*)(smA + row * 128 + pc * 16) = o;
            }
        } else {
            const u16* Ab = (const u16*)Ap;
            #pragma unroll
            for (int p = 0; p < 4; ++p) {
                int ci = p * 256 + tid;
                int row = ci >> 3, pc = ci & 7;
                int lc = pc ^ (row & 7);
                int gr = m0 + row; if (gr >= n) gr = n - 1;
                const u16* gp = Ab + (size_t)gr * K + k0 + lc * 8;
                __builtin_amdgcn_global_load_lds((const AS1 u32*)gp,
                                                 (AS3 u32*)(smA + ci * 16), 16, 0, 0);
            }
        }
        __syncthreads();                   // compiler drains vmcnt before barrier
        // ---- compute: 32 MFMA / wave / K-step ----
        const char* pa = smA + (wr * 64) * 128;
        const char* pb = smB + (wc * 64) * 128;
        #pragma unroll
        for (int kk = 0; kk < 2; ++kk) {
            const int kb = kk * 64 + kq * 16;
            bf16x8 av[4], bv[4];
            #pragma unroll
            for (int i = 0; i < 4; ++i) {
                av[i] = *(const bf16x8*)(pa + (i * 16 + r16) * 128 + (kb ^ swz));
                bv[i] = *(const bf16x8*)(pb + (i * 16 + r16) * 128 + (kb ^ swz));
            }
            #pragma unroll
            for (int mi = 0; mi < 4; ++mi)
                #pragma unroll
                for (int ni = 0; ni < 4; ++ni)
                    acc[mi][ni] = __builtin_amdgcn_mfma_f32_16x16x32_bf16(
                        av[mi], bv[ni], acc[mi][ni], 0, 0, 0);
        }
    }

    // ---- epilogue: C/D layout col = lane&15, row = (lane>>4)*4 + reg ----
    if constexpr (QKVS) {
        const int q = o0 >> 9;             // BN=128 divides 512 -> block-uniform
        u16* outp = (q == 0) ? oQ : (q == 1) ? oK : (q == 2) ? oV : oS;
        const int cb = (o0 & 511) + wc * 64;
        #pragma unroll
        for (int ni = 0; ni < 4; ++ni) {
            int col = cb + ni * 16 + r16;
            float b = bias[o0 + wc * 64 + ni * 16 + r16];
            #pragma unroll
            for (int mi = 0; mi < 4; ++mi)
                #pragma unroll
                for (int r = 0; r < 4; ++r) {
                    int gr = m0 + wr * 64 + mi * 16 + kq * 4 + r;
                    if (gr < n) outp[(size_t)gr * 512 + col] = f2bf(acc[mi][ni][r] + b);
                }
        }
    } else {
        const int cb = o0 + wc * 64;
        #pragma unroll
        for (int ni = 0; ni < 4; ++ni) {
            int col = cb + ni * 16 + r16;
            float b = bias[col];
            #pragma unroll
            for (int mi = 0; mi < 4; ++mi)
                #pragma unroll
                for (int r = 0; r < 4; ++r) {
                    int gr = m0 + wr * 64 + mi * 16 + kq * 4 + r;
                    if (gr < n) oF[(size_t)gr * Ototal + col] = acc[mi][ni][r] + b;
                }
        }
    }
}

// ---------------------------------------------------------------------------
// weight fp32 -> bf16 convert (count % 8 == 0)
__global__ __launch_bounds__(256)
void cvt_w(const float* __restrict__ src, u16* __restrict__ dst, int n8)
{
    int i = blockIdx.x * 256 + threadIdx.x;
    if (i >= n8) return;
    const float4* s = (const float4*)src + (size_t)i * 2;
    float4 f0 = s[0], f1 = s[1];
    uint4 o;
    o.x = pack2(f0.x, f0.y); o.y = pack2(f0.z, f0.w);
    o.z = pack2(f1.x, f1.y); o.w = pack2(f1.z, f1.w);
    ((uint4*)dst)[i] = o;
}

// bias arena: [0..2047]=layer0 qkvs, [2048..4095]=layer1 qkvs, [4096..4479]=out
__global__ __launch_bounds__(256)
void pack_bias(const float* q0, const float* k0, const float* v0, const float* s0,
               const float* q1, const float* k1, const float* v1, const float* s1,
               const float* ob, float* __restrict__ dst)
{
    int i = blockIdx.x * 256 + threadIdx.x;
    if (i >= 4480) return;
    float v;
    if (i < 2048) {
        int j = i & 511, q = i >> 9;
        v = (q == 0 ? q0 : q == 1 ? k0 : q == 2 ? v0 : s0)[j];
    } else if (i < 4096) {
        int j = i - 2048; int q = j >> 9; j &= 511;
        v = (q == 0 ? q1 : q == 1 ? k1 : q == 2 ? v1 : s1)[j];
    } else {
        v = ob[i - 4096];
    }
    dst[i] = v;
}

// ---------------------------------------------------------------------------
// CSR build (order within bucket nondeterministic -> only permutes fp adds)
// ---------------------------------------------------------------------------
__global__ __launch_bounds__(256)
void zero_deg(int* __restrict__ deg)
{
    int i = blockIdx.x * 256 + threadIdx.x;
    if (i < NN) deg[i] = 0;
}

__global__ __launch_bounds__(256)
void hist_dst(const int* __restrict__ dst, int* __restrict__ deg)
{
    int e = blockIdx.x * 256 + threadIdx.x;
    if (e < NE) atomicAdd(&deg[dst[e]], 1);
}

__global__ __launch_bounds__(1024)
void scan_deg(const int* __restrict__ deg, int* __restrict__ rowptr,
              int* __restrict__ cursor)
{
    __shared__ int buf[1024];
    __shared__ int carry;
    int tid = threadIdx.x;
    if (tid == 0) carry = 0;
    __syncthreads();
    for (int base = 0; base < NN; base += 1024) {
        int i = base + tid;
        int v = (i < NN) ? deg[i] : 0;
        buf[tid] = v;
        __syncthreads();
        #pragma unroll
        for (int off = 1; off < 1024; off <<= 1) {
            int t = (tid >= off) ? buf[tid - off] : 0;
            __syncthreads();
            buf[tid] += t;
            __syncthreads();
        }
        int excl = carry + buf[tid] - v;
        if (i < NN) { rowptr[i] = excl; cursor[i] = excl; }
        __syncthreads();
        if (tid == 0) carry += buf[1023];
        __syncthreads();
    }
    if (tid == 0) rowptr[NN] = NE;
}

__global__ __launch_bounds__(256)
void scatter_edges(const int* __restrict__ src, const int* __restrict__ dst,
                   int* __restrict__ cursor, int* __restrict__ esrc_ord)
{
    int e = blockIdx.x * 256 + threadIdx.x;
    if (e >= NE) return;
    int pos = atomicAdd(&cursor[dst[e]], 1);
    esrc_ord[pos] = src[e];
}

// ---------------------------------------------------------------------------
// Fused per-node attention: one 64-lane wave per dst node; online softmax.
// Lane owns 8 contiguous channels; 16-lane group = one head.
// out = bf16(relu(agg + skip)), skip is bf16.
// ---------------------------------------------------------------------------
__global__ __launch_bounds__(256)
void node_attn(const u16* __restrict__ Qb, const u16* __restrict__ Kb,
               const u16* __restrict__ Vb, const int* __restrict__ rowptr,
               const int* __restrict__ esrc, const u16* __restrict__ skipb,
               u16* __restrict__ outb)
{
    int d = blockIdx.x * 4 + (threadIdx.x >> 6);
    if (d >= NN) return;
    int lane = threadIdx.x & 63;

    uint4 qv = *((const uint4*)(Qb + (size_t)d * HC) + lane);
    float q[8] = { bflo(qv.x), bfhi(qv.x), bflo(qv.y), bfhi(qv.y),
                   bflo(qv.z), bfhi(qv.z), bflo(qv.w), bfhi(qv.w) };

    int beg = rowptr[d], end = rowptr[d + 1];
    float m = -INFINITY, den = 0.f;
    float acc[8] = {};

    for (int i = beg; i < end; ++i) {
        int s = esrc[i];
        uint4 kv = *((const uint4*)(Kb + (size_t)s * HC) + lane);
        float sum = q[0] * bflo(kv.x) + q[1] * bfhi(kv.x)
                  + q[2] * bflo(kv.y) + q[3] * bfhi(kv.y)
                  + q[4] * bflo(kv.z) + q[5] * bfhi(kv.z)
                  + q[6] * bflo(kv.w) + q[7] * bfhi(kv.w);
        #pragma unroll
        for (int off = 1; off < 16; off <<= 1) sum += __shfl_xor(sum, off, 64);
        float alpha = sum * 0.08838834764831845f;

        float mnew  = fmaxf(m, alpha);
        float scale = __expf(m - mnew);      // first edge: exp(-inf)=0
        float p     = __expf(alpha - mnew);
        den = den * scale + p;

        uint4 vv = *((const uint4*)(Vb + (size_t)s * HC) + lane);
        acc[0] = acc[0] * scale + p * bflo(vv.x);
        acc[1] = acc[1] * scale + p * bfhi(vv.x);
        acc[2] = acc[2] * scale + p * bflo(vv.y);
        acc[3] = acc[3] * scale + p * bfhi(vv.y);
        acc[4] = acc[4] * scale + p * bflo(vv.z);
        acc[5] = acc[5] * scale + p * bfhi(vv.z);
        acc[6] = acc[6] * scale + p * bflo(vv.w);
        acc[7] = acc[7] * scale + p * bfhi(vv.w);
        m = mnew;
    }

    float inv = 1.f / (den + 1e-16f);
    size_t base = (size_t)d * HC + lane * 8;
    uint4 sv = *((const uint4*)(skipb + base));
    float sk[8] = { bflo(sv.x), bfhi(sv.x), bflo(sv.y), bfhi(sv.y),
                    bflo(sv.z), bfhi(sv.z), bflo(sv.w), bfhi(sv.w) };
    uint4 o;
    o.x = pack2(fmaxf(acc[0] * inv + sk[0], 0.f), fmaxf(acc[1] * inv + sk[1], 0.f));
    o.y = pack2(fmaxf(acc[2] * inv + sk[2], 0.f), fmaxf(acc[3] * inv + sk[3], 0.f));
    o.z = pack2(fmaxf(acc[4] * inv + sk[4], 0.f), fmaxf(acc[5] * inv + sk[5], 0.f));
    o.w = pack2(fmaxf(acc[6] * inv + sk[6], 0.f), fmaxf(acc[7] * inv + sk[7], 0.f));
    *(uint4*)(outb + base) = o;
}

// ---------------------------------------------------------------------------
extern "C" void kernel_launch(void* const* d_in, const int* in_sizes, int n_in,
                              void* d_out, int out_size, void* d_ws, size_t ws_size,
                              hipStream_t stream)
{
    const float* x   = (const float*)d_in[0];
    const int* ei    = (const int*)d_in[1];
    const int* esrc  = ei;
    const int* edst  = ei + NE;
    const float* q0w = (const float*)d_in[2];  const float* q0b = (const float*)d_in[3];
    const float* k0w = (const float*)d_in[4];  const float* k0b = (const float*)d_in[5];
    const float* v0w = (const float*)d_in[6];  const float* v0b = (const float*)d_in[7];
    const float* s0w = (const float*)d_in[8];  const float* s0b = (const float*)d_in[9];
    const float* q1w = (const float*)d_in[10]; const float* q1b = (const float*)d_in[11];
    const float* k1w = (const float*)d_in[12]; const float* k1b = (const float*)d_in[13];
    const float* v1w = (const float*)d_in[14]; const float* v1b = (const float*)d_in[15];
    const float* s1w = (const float*)d_in[16]; const float* s1b = (const float*)d_in[17];
    const float* ow  = (const float*)d_in[18]; const float* obs = (const float*)d_in[19];

    // ---- workspace (~209 MB) ----
    char* p = (char*)d_ws;
    auto take = [&](size_t bytes) { void* r = (void*)p; p += (bytes + 255) & ~(size_t)255; return r; };
    u16*   Qb     = (u16*)take((size_t)NN * HC * 2);       // 51.2 MB
    u16*   Vb     = (u16*)take((size_t)NN * HC * 2);       // 51.2 MB
    u16*   Hb     = (u16*)take((size_t)NN * HC * 2);       // 51.2 MB
    u16*   Sb     = (u16*)take((size_t)NN * HC * 2);       // 51.2 MB (bf16 skip)
    u16*   Wc0    = (u16*)take((size_t)2048 * DD * 2);     // 1.57 MB
    u16*   Wc1    = (u16*)take((size_t)2048 * HC * 2);     // 2.10 MB
    u16*   WcO    = (u16*)take((size_t)DD * HC * 2);       // 0.39 MB
    float* barena = (float*)take(4480 * 4);                // 17.9 KB

    // ---- scratch carved from d_out (dead before final GEMM overwrites all) ----
    char* dob = (char*)d_out;
    u16* Kb       = (u16*)dob;                             // 51.2 MB
    int* deg      = (int*)(dob + 51200000);
    int* rowptr   = (int*)(dob + 51400192);                // NN+1
    int* cursor   = (int*)(dob + 51600384);
    int* esrc_ord = (int*)(dob + 51800576);                // 1.6 MB

    dim3 blk(256);
    int gN   = (NN + 255) / 256;
    int gE   = (NE + 255) / 256;
    int gnod = (NN + 3) / 4;
    const int NPAN = (NN + 127) / 128;   // 391 row panels
    int gq = NPAN * 16;                  // QKVS GEMM: 16 col-tiles
    int go = NPAN * 3;                   // out-proj: 3 col-tiles

    // ---- weight/bias prep ----
    pack_bias<<<(4480 + 255) / 256, blk, 0, stream>>>(q0b, k0b, v0b, s0b,
                                                      q1b, k1b, v1b, s1b, obs, barena);
    const int w0n8 = 512 * DD / 8, w1n8 = 512 * HC / 8, won8 = DD * HC / 8;
    cvt_w<<<(w0n8 + 255) / 256, blk, 0, stream>>>(q0w, Wc0 + 0 * 512 * DD, w0n8);
    cvt_w<<<(w0n8 + 255) / 256, blk, 0, stream>>>(k0w, Wc0 + 1 * 512 * DD, w0n8);
    cvt_w<<<(w0n8 + 255) / 256, blk, 0, stream>>>(v0w, Wc0 + 2 * 512 * DD, w0n8);
    cvt_w<<<(w0n8 + 255) / 256, blk, 0, stream>>>(s0w, Wc0 + 3 * 512 * DD, w0n8);
    cvt_w<<<(w1n8 + 255) / 256, blk, 0, stream>>>(q1w, Wc1 + 0 * 512 * HC, w1n8);
    cvt_w<<<(w1n8 + 255) / 256, blk, 0, stream>>>(k1w, Wc1 + 1 * 512 * HC, w1n8);
    cvt_w<<<(w1n8 + 255) / 256, blk, 0, stream>>>(v1w, Wc1 + 2 * 512 * HC, w1n8);
    cvt_w<<<(w1n8 + 255) / 256, blk, 0, stream>>>(s1w, Wc1 + 3 * 512 * HC, w1n8);
    cvt_w<<<(won8 + 255) / 256, blk, 0, stream>>>(ow, WcO, won8);

    // ---- CSR build ----
    zero_deg      <<<gN, blk, 0, stream>>>(deg);
    hist_dst      <<<gE, blk, 0, stream>>>(edst, deg);
    scan_deg      <<<1, 1024, 0, stream>>>(deg, rowptr, cursor);
    scatter_edges <<<gE, blk, 0, stream>>>(esrc, edst, cursor, esrc_ord);

    // ---- layer 0 (A = x fp32, K=384) ----
    gemm_mfma<true, true><<<gq, blk, 0, stream>>>(x, Wc0, barena,
                                                  Qb, Kb, Vb, Sb, nullptr, NN, DD, 2048, 16);
    node_attn<<<gnod, blk, 0, stream>>>(Qb, Kb, Vb, rowptr, esrc_ord, Sb, Hb);

    // ---- layer 1 (A = Hb bf16, K=512) ----
    gemm_mfma<false, true><<<gq, blk, 0, stream>>>(Hb, Wc1, barena + 2048,
                                                   Qb, Kb, Vb, Sb, nullptr, NN, HC, 2048, 16);
    node_attn<<<gnod, blk, 0, stream>>>(Qb, Kb, Vb, rowptr, esrc_ord, Sb, Hb);

    // ---- output projection (fp32 out, overwrites ALL of d_out) ----
    gemm_mfma<false, false><<<go, blk, 0, stream>>>(Hb, WcO, barena + 4096,
                                                    nullptr, nullptr, nullptr, nullptr,
                                                    (float*)d_out, NN, HC, DD, 3);
}